// Round 1
// baseline (306.475 us; speedup 1.0000x reference)
//
#include <hip/hip_runtime.h>

// ReactionTerm: y_out[b,p] = sum_r1 [p==inds_1p[r]] * y[b,inds_1r[r]] * t[b]*k1[r]
//             + sum_r2 [p==inds_2p[r]] * y[b,i2r[r,0]]*y[b,i2r[r,1]] * t[b]*k2[r]
//
// Strategy: one block handles G batch rows. Stage y rows + accumulators in LDS.
// Reaction/index data (shared across all rows) is read once per block and applied
// to all G rows from registers -> amortizes L2 index traffic and address math.
// Scatter-add via LDS f32 atomics (ds_add_f32).

constexpr int BATCH   = 4096;
constexpr int NS      = 1024;
constexpr int NR1     = 2048;
constexpr int NR2     = 8192;
constexpr int G       = 4;     // batch rows per block
constexpr int NTHREADS = 256;

__global__ __launch_bounds__(NTHREADS) void reaction_kernel(
    const float* __restrict__ t_in,   // [B]
    const float* __restrict__ y_in,   // [B, NS]
    const float* __restrict__ k1,     // [NR1]
    const float* __restrict__ k2,     // [NR2]
    const int*   __restrict__ i1r,    // [NR1]
    const int*   __restrict__ i1p,    // [NR1]
    const int*   __restrict__ i2r,    // [NR2, 2]
    const int*   __restrict__ i2p,    // [NR2]
    float*       __restrict__ y_out)  // [B, NS]
{
    __shared__ float y_s[G][NS];
    __shared__ float a_s[G][NS];

    const int tid = threadIdx.x;
    const int b0  = blockIdx.x * G;

    // Stage y rows into LDS (coalesced float4) and zero accumulators.
    #pragma unroll
    for (int g = 0; g < G; ++g) {
        const float4* src = (const float4*)(y_in + (size_t)(b0 + g) * NS);
        float4* ydst = (float4*)(&y_s[g][0]);
        float4* adst = (float4*)(&a_s[g][0]);
        const float4 z = {0.f, 0.f, 0.f, 0.f};
        for (int i = tid; i < NS / 4; i += NTHREADS) {
            ydst[i] = src[i];
            adst[i] = z;
        }
    }

    float t[G];
    #pragma unroll
    for (int g = 0; g < G; ++g) t[g] = t_in[b0 + g];

    __syncthreads();

    // First-order reactions: term = y[ir] * (t*k); scatter-add to ip.
    for (int r = tid; r < NR1; r += NTHREADS) {
        const int   ir = i1r[r];
        const int   ip = i1p[r];
        const float k  = k1[r];
        #pragma unroll
        for (int g = 0; g < G; ++g) {
            atomicAdd(&a_s[g][ip], y_s[g][ir] * (t[g] * k));
        }
    }

    // Second-order reactions: term = y[ia]*y[ib] * (t*k); scatter-add to ip.
    const int2* __restrict__ i2r2 = (const int2*)i2r;
    for (int r = tid; r < NR2; r += NTHREADS) {
        const int2  ab = i2r2[r];
        const int   ip = i2p[r];
        const float k  = k2[r];
        #pragma unroll
        for (int g = 0; g < G; ++g) {
            atomicAdd(&a_s[g][ip], y_s[g][ab.x] * y_s[g][ab.y] * (t[g] * k));
        }
    }

    __syncthreads();

    // Write rows back (coalesced float4).
    #pragma unroll
    for (int g = 0; g < G; ++g) {
        const float4* asrc = (const float4*)(&a_s[g][0]);
        float4* dst = (float4*)(y_out + (size_t)(b0 + g) * NS);
        for (int i = tid; i < NS / 4; i += NTHREADS) {
            dst[i] = asrc[i];
        }
    }
}

extern "C" void kernel_launch(void* const* d_in, const int* in_sizes, int n_in,
                              void* d_out, int out_size, void* d_ws, size_t ws_size,
                              hipStream_t stream) {
    const float* t_in = (const float*)d_in[0];
    const float* y_in = (const float*)d_in[1];
    const float* k1   = (const float*)d_in[2];
    const float* k2   = (const float*)d_in[3];
    const int*   i1r  = (const int*)d_in[4];
    const int*   i1p  = (const int*)d_in[5];
    const int*   i2r  = (const int*)d_in[6];
    const int*   i2p  = (const int*)d_in[7];
    float*       out  = (float*)d_out;

    dim3 grid(BATCH / G);
    dim3 block(NTHREADS);
    reaction_kernel<<<grid, block, 0, stream>>>(t_in, y_in, k1, k2,
                                                i1r, i1p, i2r, i2p, out);
}

// Round 3
// 132.553 us; speedup vs baseline: 2.3121x; 2.3121x over previous
//
#include <hip/hip_runtime.h>

// ReactionTerm — gather formulation (no atomics in the hot kernel).
//
// build_kernel (1 block, 1024 threads): histogram reactions by PRODUCT species
// in LDS, Hillis-Steele scan in LDS, scatter packed records to global ws:
//   record[j] = int2{ ia | (ib << 16), bitcast(k) }
// sorted so records for product p occupy [off[p], off[p+1]).
// First-order reactions use ib = NS (sentinel); main kernel's y_s[NS] = 1.0f.
//
// reaction_main_kernel: one block = G=4 batch rows x all 1024 products.
// LDS tile TRANSPOSED: y_s[s] = float4{y[b0+0][s], .., y[b0+3][s]} so each
// record needs just 2 ds_read_b128. Thread owns products {2*tid, 2*tid+1};
// register accumulation; coalesced float2 stores. Zero atomics, 32 waves/CU.

constexpr int BATCH = 4096;
constexpr int NS    = 1024;
constexpr int NR1   = 2048;
constexpr int NR2   = 8192;
constexpr int NRT   = NR1 + NR2;   // 10240
constexpr int G     = 4;
constexpr int MAIN_THREADS = 512;

// d_ws layout (bytes) — NO overlaps:
//   off    : int[1025]   @ 0      (4100 B, ends 4100)
//   records: int2[10240] @ 8192   (81920 B, ends 90112)
constexpr size_t WS_OFF     = 0;
constexpr size_t WS_RECORDS = 8192;

__global__ __launch_bounds__(1024) void build_kernel(
    const float* __restrict__ k1,  const float* __restrict__ k2,
    const int*   __restrict__ i1r, const int*   __restrict__ i1p,
    const int*   __restrict__ i2r, const int*   __restrict__ i2p,
    int*         __restrict__ off_g,    // [NS+1]
    int2*        __restrict__ records)  // [NRT]
{
    __shared__ int sA[NS];
    __shared__ int sB[NS];
    __shared__ int cur[NS];
    const int tid = threadIdx.x;

    // histogram by product
    sA[tid] = 0;
    __syncthreads();
    for (int i = tid; i < NR1; i += 1024) atomicAdd(&sA[i1p[i]], 1);
    for (int i = tid; i < NR2; i += 1024) atomicAdd(&sA[i2p[i]], 1);
    __syncthreads();
    const int c = sA[tid];

    // inclusive scan (Hillis-Steele, ping-pong sA/sB)
    int* a = sA;
    int* b = sB;
    for (int d = 1; d < NS; d <<= 1) {
        int v = a[tid];
        if (tid >= d) v += a[tid - d];
        b[tid] = v;
        __syncthreads();
        int* tmp = a; a = b; b = tmp;
    }
    const int incl = a[tid];
    off_g[tid + 1] = incl;
    if (tid == 0) off_g[0] = 0;
    cur[tid] = incl - c;          // exclusive prefix = segment start
    __syncthreads();

    // scatter packed records
    for (int i = tid; i < NR1; i += 1024) {
        const int pos = atomicAdd(&cur[i1p[i]], 1);
        records[pos] = make_int2(i1r[i] | (NS << 16), __float_as_int(k1[i]));
    }
    for (int i = tid; i < NR2; i += 1024) {
        const int pos = atomicAdd(&cur[i2p[i]], 1);
        records[pos] = make_int2(i2r[2 * i] | (i2r[2 * i + 1] << 16),
                                 __float_as_int(k2[i]));
    }
}

__global__ __launch_bounds__(MAIN_THREADS) void reaction_main_kernel(
    const float* __restrict__ t_in,     // [B]
    const float* __restrict__ y_in,     // [B, NS]
    const int*   __restrict__ off,      // [NS+1]
    const int2*  __restrict__ records,  // [NRT]
    float*       __restrict__ y_out)    // [B, NS]
{
    __shared__ float4 y_s[NS + 1];      // y_s[s] = {y[b0+g][s]}_{g=0..3}; [NS] = 1.0 sentinel

    const int tid = threadIdx.x;
    const int b0  = blockIdx.x * G;

    // Stage transposed tile: ys[s*4+g] = y_in[b0+g][s]
    float* ys = (float*)y_s;
    for (int f = tid; f < NS * G; f += MAIN_THREADS) {
        const int s = f >> 2;
        const int g = f & 3;
        ys[f] = y_in[(size_t)(b0 + g) * NS + s];
    }
    if (tid == 0) y_s[NS] = make_float4(1.f, 1.f, 1.f, 1.f);
    __syncthreads();

    const int p0 = tid * 2;
    const int s0 = off[p0];
    const int s1 = off[p0 + 1];
    const int s2 = off[p0 + 2];

    float4 acc0 = {0.f, 0.f, 0.f, 0.f};
    float4 acc1 = {0.f, 0.f, 0.f, 0.f};

    for (int j = s0; j < s1; ++j) {
        const int2 r = records[j];
        const unsigned ix = (unsigned)r.x;
        const float4 ya = y_s[ix & 0xFFFFu];
        const float4 yb = y_s[ix >> 16];
        const float  k  = __int_as_float(r.y);
        acc0.x += k * ya.x * yb.x;
        acc0.y += k * ya.y * yb.y;
        acc0.z += k * ya.z * yb.z;
        acc0.w += k * ya.w * yb.w;
    }
    for (int j = s1; j < s2; ++j) {
        const int2 r = records[j];
        const unsigned ix = (unsigned)r.x;
        const float4 ya = y_s[ix & 0xFFFFu];
        const float4 yb = y_s[ix >> 16];
        const float  k  = __int_as_float(r.y);
        acc1.x += k * ya.x * yb.x;
        acc1.y += k * ya.y * yb.y;
        acc1.z += k * ya.z * yb.z;
        acc1.w += k * ya.w * yb.w;
    }

    const float t0 = t_in[b0];
    const float t1 = t_in[b0 + 1];
    const float t2 = t_in[b0 + 2];
    const float t3 = t_in[b0 + 3];

    *(float2*)(y_out + (size_t)(b0 + 0) * NS + p0) = make_float2(acc0.x * t0, acc1.x * t0);
    *(float2*)(y_out + (size_t)(b0 + 1) * NS + p0) = make_float2(acc0.y * t1, acc1.y * t1);
    *(float2*)(y_out + (size_t)(b0 + 2) * NS + p0) = make_float2(acc0.z * t2, acc1.z * t2);
    *(float2*)(y_out + (size_t)(b0 + 3) * NS + p0) = make_float2(acc0.w * t3, acc1.w * t3);
}

extern "C" void kernel_launch(void* const* d_in, const int* in_sizes, int n_in,
                              void* d_out, int out_size, void* d_ws, size_t ws_size,
                              hipStream_t stream) {
    const float* t_in = (const float*)d_in[0];
    const float* y_in = (const float*)d_in[1];
    const float* k1   = (const float*)d_in[2];
    const float* k2   = (const float*)d_in[3];
    const int*   i1r  = (const int*)d_in[4];
    const int*   i1p  = (const int*)d_in[5];
    const int*   i2r  = (const int*)d_in[6];
    const int*   i2p  = (const int*)d_in[7];
    float*       out  = (float*)d_out;

    char* ws = (char*)d_ws;
    int*  off     = (int*)(ws + WS_OFF);
    int2* records = (int2*)(ws + WS_RECORDS);

    build_kernel<<<dim3(1), dim3(1024), 0, stream>>>(
        k1, k2, i1r, i1p, i2r, i2p, off, records);
    reaction_main_kernel<<<dim3(BATCH / G), dim3(MAIN_THREADS), 0, stream>>>(
        t_in, y_in, off, records, out);
}

// Round 4
// 102.303 us; speedup vs baseline: 2.9958x; 1.2957x over previous
//
#include <hip/hip_runtime.h>

// ReactionTerm — gather formulation, ELL-transposed record layout.
//
// Build (cheap, no scan):
//   hipMemsetAsync zeroes counts[1024] + ell[64][1024] (int2 records).
//   fill_kernel: slot = atomicAdd(count[p]) ; ell[slot][p] = {ia|(ib<<16), k_bits}
//   First-order reactions use ib = NS (sentinel); y_s[NS] = 1.0f.
//   Zero slots decode to {ia=0, ib=0, k=0} -> contribute exactly 0.
//
// reaction_main_kernel: one block = G=4 batch rows x all 1024 products.
// LDS tile transposed: y_s[s] = float4{y[b0+g][s]}. Thread t owns products
// {2t, 2t+1}; per slot it reads ONE coalesced int4 = both products' records
// (ell[slot][2t..2t+1]), 4x ds_read_b128, register FMA. Loop bound =
// max(count[2t], count[2t+1]); shorter product's pad slots add 0 via k=0.
// Zero atomics in hot kernel; 4 blocks/CU x 512 thr = 32 waves/CU.

constexpr int BATCH = 4096;
constexpr int NS    = 1024;
constexpr int NR1   = 2048;
constexpr int NR2   = 8192;
constexpr int NRT   = NR1 + NR2;   // 10240
constexpr int G     = 4;
constexpr int MAIN_THREADS = 512;
constexpr int MAX_SLOTS = 64;      // Poisson(λ≈10): P(count>=64) ~ 1e-30

// d_ws layout (bytes) — no overlaps:
//   counts : int[1024]          @ 0      (4096 B)
//   ell    : int2[64*1024]      @ 8192   (524288 B, ends 532480)
constexpr size_t WS_COUNTS = 0;
constexpr size_t WS_ELL    = 8192;
constexpr size_t WS_ZERO_BYTES = WS_ELL + (size_t)MAX_SLOTS * NS * sizeof(int2);

__global__ __launch_bounds__(256) void fill_kernel(
    const float* __restrict__ k1,  const float* __restrict__ k2,
    const int*   __restrict__ i1r, const int*   __restrict__ i1p,
    const int*   __restrict__ i2r, const int*   __restrict__ i2p,
    int*         __restrict__ counts,   // [NS]
    int2*        __restrict__ ell)      // [MAX_SLOTS][NS]
{
    const int i = blockIdx.x * blockDim.x + threadIdx.x;
    if (i < NR1) {
        const int p = i1p[i];
        const int slot = atomicAdd(&counts[p], 1);
        if (slot < MAX_SLOTS)
            ell[slot * NS + p] = make_int2(i1r[i] | (NS << 16), __float_as_int(k1[i]));
    } else if (i < NRT) {
        const int r = i - NR1;
        const int p = i2p[r];
        const int slot = atomicAdd(&counts[p], 1);
        if (slot < MAX_SLOTS)
            ell[slot * NS + p] = make_int2(i2r[2 * r] | (i2r[2 * r + 1] << 16),
                                           __float_as_int(k2[r]));
    }
}

__global__ __launch_bounds__(MAIN_THREADS) void reaction_main_kernel(
    const float* __restrict__ t_in,    // [B]
    const float* __restrict__ y_in,    // [B, NS]
    const int*   __restrict__ counts,  // [NS]
    const int4*  __restrict__ ell4,    // [MAX_SLOTS][NS/2] record-pairs
    float*       __restrict__ y_out)   // [B, NS]
{
    __shared__ float4 y_s[NS + 1];     // y_s[s] = {y[b0+g][s]}_{g=0..3}; [NS] = 1.0

    const int tid = threadIdx.x;
    const int b0  = blockIdx.x * G;

    // Stage transposed tile: coalesced float4 global loads, scalar ds_writes
    // (stride pattern is 2-way bank aliasing = free).
    {
        float* ys = (float*)y_s;
        for (int idx = tid; idx < G * (NS / 4); idx += MAIN_THREADS) {
            const int g  = idx >> 8;        // row 0..3
            const int s4 = idx & 255;       // float4 index within row
            const float4 v = ((const float4*)(y_in + (size_t)(b0 + g) * NS))[s4];
            ys[(s4 * 4 + 0) * 4 + g] = v.x;
            ys[(s4 * 4 + 1) * 4 + g] = v.y;
            ys[(s4 * 4 + 2) * 4 + g] = v.z;
            ys[(s4 * 4 + 3) * 4 + g] = v.w;
        }
        if (tid == 0) y_s[NS] = make_float4(1.f, 1.f, 1.f, 1.f);
    }
    __syncthreads();

    const int2 c2  = ((const int2*)counts)[tid];   // counts for products 2t, 2t+1
    const int cmax = max(c2.x, c2.y);

    float4 acc0 = {0.f, 0.f, 0.f, 0.f};
    float4 acc1 = {0.f, 0.f, 0.f, 0.f};

    // 1-deep software prefetch of the coalesced record-pair.
    int4 rec = (cmax > 0) ? ell4[tid] : make_int4(0, 0, 0, 0);
    for (int slot = 0; slot < cmax; ++slot) {
        const int4 nrec = (slot + 1 < cmax) ? ell4[(slot + 1) * (NS / 2) + tid]
                                            : make_int4(0, 0, 0, 0);
        {
            const unsigned ix = (unsigned)rec.x;
            const float4 ya = y_s[ix & 0xFFFFu];
            const float4 yb = y_s[ix >> 16];
            const float  k  = __int_as_float(rec.y);
            acc0.x += k * ya.x * yb.x;
            acc0.y += k * ya.y * yb.y;
            acc0.z += k * ya.z * yb.z;
            acc0.w += k * ya.w * yb.w;
        }
        {
            const unsigned ix = (unsigned)rec.z;
            const float4 ya = y_s[ix & 0xFFFFu];
            const float4 yb = y_s[ix >> 16];
            const float  k  = __int_as_float(rec.w);
            acc1.x += k * ya.x * yb.x;
            acc1.y += k * ya.y * yb.y;
            acc1.z += k * ya.z * yb.z;
            acc1.w += k * ya.w * yb.w;
        }
        rec = nrec;
    }

    const float t0 = t_in[b0];
    const float t1 = t_in[b0 + 1];
    const float t2 = t_in[b0 + 2];
    const float t3 = t_in[b0 + 3];

    const int p0 = tid * 2;
    *(float2*)(y_out + (size_t)(b0 + 0) * NS + p0) = make_float2(acc0.x * t0, acc1.x * t0);
    *(float2*)(y_out + (size_t)(b0 + 1) * NS + p0) = make_float2(acc0.y * t1, acc1.y * t1);
    *(float2*)(y_out + (size_t)(b0 + 2) * NS + p0) = make_float2(acc0.z * t2, acc1.z * t2);
    *(float2*)(y_out + (size_t)(b0 + 3) * NS + p0) = make_float2(acc0.w * t3, acc1.w * t3);
}

extern "C" void kernel_launch(void* const* d_in, const int* in_sizes, int n_in,
                              void* d_out, int out_size, void* d_ws, size_t ws_size,
                              hipStream_t stream) {
    const float* t_in = (const float*)d_in[0];
    const float* y_in = (const float*)d_in[1];
    const float* k1   = (const float*)d_in[2];
    const float* k2   = (const float*)d_in[3];
    const int*   i1r  = (const int*)d_in[4];
    const int*   i1p  = (const int*)d_in[5];
    const int*   i2r  = (const int*)d_in[6];
    const int*   i2p  = (const int*)d_in[7];
    float*       out  = (float*)d_out;

    char* ws = (char*)d_ws;
    int*  counts = (int*)(ws + WS_COUNTS);
    int2* ell    = (int2*)(ws + WS_ELL);

    // Zero counts + ELL records (pad slots must decode to k=0).
    hipMemsetAsync(ws, 0, WS_ZERO_BYTES, stream);
    fill_kernel<<<dim3((NRT + 255) / 256), dim3(256), 0, stream>>>(
        k1, k2, i1r, i1p, i2r, i2p, counts, ell);
    reaction_main_kernel<<<dim3(BATCH / G), dim3(MAIN_THREADS), 0, stream>>>(
        t_in, y_in, counts, (const int4*)ell, out);
}